// Round 4
// baseline (65.765 us; speedup 1.0000x reference)
//
#include <hip/hip_runtime.h>
#include <math.h>

#define BB 4
#define NN 4096
#define DD 128
#define MSPLIT 8          // m-space split across blocks
#define NIT 8             // half-tiles (64 m-rows) per block
#define TM 64             // m rows per half-tile
#define NP 128            // column-argmax partials per m (32 tn * 4 waves)

typedef __attribute__((ext_vector_type(8))) short bf16x8;
typedef __attribute__((ext_vector_type(4))) float f32x4;

__device__ __forceinline__ void mfma_16x16x32_bf16(f32x4& d, bf16x8 a, bf16x8 b) {
  asm volatile("v_mfma_f32_16x16x32_bf16 %0, %1, %2, %0" : "+v"(d) : "v"(a), "v"(b));
}

__device__ __forceinline__ void gload16(const void* g, void* lds) {
  __builtin_amdgcn_global_load_lds(
      (const __attribute__((address_space(1))) void*)g,
      (__attribute__((address_space(3))) void*)lds, 16, 0, 0);
}

__device__ __forceinline__ unsigned short f2b(float x) {  // RNE f32->bf16
  union { float f; unsigned u; } v; v.f = x;
  unsigned r = v.u + 0x7fffu + ((v.u >> 16) & 1u);
  return (unsigned short)(r >> 16);
}

// ---- kernel 1: cast to bf16 (ft pre-scaled by 0.1*log2e) + fs inv-norms ----
// one wave per 128-elem row; rows [0,16384) = fs, [16384,32768) = ft.
__global__ __launch_bounds__(256) void k_prep(const float* __restrict__ fs,
                                              const float* __restrict__ ft,
                                              unsigned* __restrict__ outb,
                                              float* __restrict__ inv_norm) {
  int w = threadIdx.x >> 6, lane = threadIdx.x & 63;
  int row = blockIdx.x * 4 + w;
  bool is_s = row < BB * NN;
  const float* src = is_s ? fs + (size_t)row * DD
                          : ft + ((size_t)row - BB * NN) * DD;
  float2 v = ((const float2*)src)[lane];
  const float C = 0.14426950408889634f;   // 0.1 * log2(e): exp(dot/10) == 2^acc
  float cx = is_s ? v.x : v.x * C;
  float cy = is_s ? v.y : v.y * C;
  outb[(size_t)row * 64 + lane] = ((unsigned)f2b(cy) << 16) | f2b(cx);
  if (is_s) {
    float s = v.x * v.x + v.y * v.y;
#pragma unroll
    for (int off = 32; off > 0; off >>= 1) s += __shfl_xor(s, off);
    if (lane == 0) inv_norm[row] = 1.0f / sqrtf(s);
  }
}

// ---- kernel 2: persistent-A MFMA GEMM + fused 2^x rowsum + scaled colmax ---
// block (tn, h, b): A = 128 n-rows held as register fragments (wave w owns
// rows w*32..w*32+31 x full K), loop over 8 half-tiles of 64 m-rows with
// 1-deep global_load_lds prefetch and ONE barrier per tile. Column argmax
// partials (4 per column) go straight to global; row exp-sums accumulate in
// registers for the whole block.
__global__ __launch_bounds__(256, 4) void k_main(const unsigned short* __restrict__ fsb,
                                                 const unsigned short* __restrict__ ftb,
                                                 const float* __restrict__ inv_norm,
                                                 float* __restrict__ psum,
                                                 float2* __restrict__ pmaxvi) {
  __shared__ __align__(16) char smem[32768];   // A stage / 2x16KB B dbuf

  const int t = threadIdx.x;
  const int tn = blockIdx.x, h = blockIdx.y, b = blockIdx.z;
  const int w = t >> 6, lane = t & 63;
  const int l15 = lane & 15, g = lane >> 4;

  // staging constants: 16B-block swizzle col' = col ^ (row & 15)
  const int t16 = t >> 4, cp = t & 15;
  const int srcThr = t16 * 256 + ((cp ^ (t16 & 15)) << 4);
  const int ldsThr = w * 1024;                 // wave-uniform LDS base

  const char* gA = (const char*)(fsb + ((size_t)b * NN + (size_t)tn * 128) * DD);
  const char* gB0 = (const char*)(ftb + ((size_t)b * NN + (size_t)h * (NIT * TM)) * DD);

  // stage full A tile (32KB)
#pragma unroll
  for (int p = 0; p < 8; p++)
    gload16(gA + p * 4096 + srcThr, smem + p * 4096 + ldsThr);
  __syncthreads();

  // A fragments: rows w*32 + fi*16 + l15 (fi = 0..1), all K
  bf16x8 af[4][2];
#pragma unroll
  for (int kk = 0; kk < 4; kk++)
#pragma unroll
    for (int fi = 0; fi < 2; fi++) {
      int Ra = w * 32 + fi * 16 + l15;
      af[kk][fi] = *(const bf16x8*)(smem + Ra * 256 + (((kk * 4 + g) ^ l15) << 4));
    }
  // per-row inv norms + row ids for this thread's 8 acc rows
  float sv[2][4];
  int rowid[2][4];
  const float* invb = inv_norm + (size_t)b * NN + tn * 128 + w * 32 + g * 4;
#pragma unroll
  for (int fi = 0; fi < 2; fi++)
#pragma unroll
    for (int j = 0; j < 4; j++) {
      sv[fi][j] = invb[fi * 16 + j];
      rowid[fi][j] = w * 32 + fi * 16 + g * 4 + j;
    }
  __syncthreads();   // all A reads done -> smem free for B tiles

  char* cb = smem;           // compute half-tile
  char* nb = smem + 16384;   // prefetch half-tile

  // stage B half-tile 0
#pragma unroll
  for (int p = 0; p < 4; p++)
    gload16(gB0 + p * 4096 + srcThr, cb + p * 4096 + ldsThr);

  float rowacc[2][4] = {};

  for (int it = 0; it < NIT; ++it) {
    __syncthreads();   // drains this wave's B_it prefetch; publishes it block-wide
    // prefetch B_{it+1} (in flight across the whole compute phase)
    if (it + 1 < NIT) {
      const char* gBn = gB0 + (size_t)(it + 1) * (TM * DD * 2);
#pragma unroll
      for (int p = 0; p < 4; p++)
        gload16(gBn + p * 4096 + srcThr, nb + p * 4096 + ldsThr);
    }
    // MFMA: 32 n-rows x 64 m-cols, K=128
    f32x4 acc[2][4] = {};
#pragma unroll
    for (int kk = 0; kk < 4; kk++) {
      bf16x8 bfr[4];
#pragma unroll
      for (int fj = 0; fj < 4; fj++) {
        int Rb = fj * 16 + l15;
        bfr[fj] = *(const bf16x8*)(cb + Rb * 256 + (((kk * 4 + g) ^ l15) << 4));
      }
#pragma unroll
      for (int fi = 0; fi < 2; fi++)
#pragma unroll
        for (int fj = 0; fj < 4; fj++)
          mfma_16x16x32_bf16(acc[fi][fj], af[kk][fi], bfr[fj]);
    }
    // epilogue 3a: exp row-sums (acc == dot*0.1*log2e, so 2^acc == exp(dot/10))
#pragma unroll
    for (int fi = 0; fi < 2; fi++)
#pragma unroll
      for (int j = 0; j < 4; j++) {
        float s = (exp2f(acc[fi][0][j]) + exp2f(acc[fi][1][j])) +
                  (exp2f(acc[fi][2][j]) + exp2f(acc[fi][3][j]));
        rowacc[fi][j] += s;
      }
    // epilogue 3b: per-column argmax of acc*inv_norm (ascending rows, strict >)
#pragma unroll
    for (int fj = 0; fj < 4; fj++) {
      float bv = -INFINITY; int bi = 0x7fffffff;
#pragma unroll
      for (int fi = 0; fi < 2; fi++)
#pragma unroll
        for (int j = 0; j < 4; j++) {
          float vv = acc[fi][fj][j] * sv[fi][j];
          if (vv > bv) { bv = vv; bi = rowid[fi][j]; }
        }
#pragma unroll
      for (int off = 16; off <= 32; off <<= 1) {   // reduce over g
        float ov = __shfl_xor(bv, off);
        int   oi = __shfl_xor(bi, off);
        if (ov > bv || (ov == bv && oi < bi)) { bv = ov; bi = oi; }
      }
      if (g == 0) {
        int m = (h * NIT + it) * TM + fj * 16 + l15;
        float2 pr; pr.x = bv; pr.y = __int_as_float(tn * 128 + bi);
        pmaxvi[((size_t)b * NN + m) * NP + tn * 4 + w] = pr;
      }
    }
    char* tmp = cb; cb = nb; nb = tmp;
  }

  // final row-sum partials: reduce over the 16 l15 lanes, store per h
#pragma unroll
  for (int fi = 0; fi < 2; fi++)
#pragma unroll
    for (int j = 0; j < 4; j++) {
      float s = rowacc[fi][j];
#pragma unroll
      for (int off = 1; off <= 8; off <<= 1) s += __shfl_xor(s, off);
      if (l15 == 0) {
        int n = tn * 128 + w * 32 + fi * 16 + g * 4 + j;
        psum[((size_t)b * NN + n) * MSPLIT + h] = s;
      }
    }
}

// ---- kernel 3: per-row finish: argmax over 128 partials, log-sum, pos dot --
__global__ __launch_bounds__(256) void k_post(const float* __restrict__ fs,
                                              const float* __restrict__ ft,
                                              const float* __restrict__ psum,
                                              const float2* __restrict__ pmaxvi,
                                              float* __restrict__ blockpart) {
  __shared__ float part[4];
  int w = threadIdx.x >> 6, lane = threadIdx.x & 63;
  int row = blockIdx.x * 4 + w;          // flat b*N + m
  int b = row >> 12;
  const float2* pp = pmaxvi + (size_t)row * NP;
  float2 p0 = pp[lane], p1 = pp[lane + 64];
  float v = p0.x; int i = __float_as_int(p0.y);
  {
    int i1 = __float_as_int(p1.y);
    if (p1.x > v || (p1.x == v && i1 < i)) { v = p1.x; i = i1; }
  }
#pragma unroll
  for (int off = 32; off > 0; off >>= 1) {
    float ov = __shfl_xor(v, off);
    int   oi = __shfl_xor(i, off);
    if (ov > v || (ov == v && oi < i)) { v = ov; i = oi; }
  }
  // fp32 dot of fs[row] with ft[b, i]
  float2 a = ((const float2*)(fs + (size_t)row * DD))[lane];
  float2 c = ((const float2*)(ft + ((size_t)b * NN + i) * DD))[lane];
  float s = a.x * c.x + a.y * c.y;
#pragma unroll
  for (int off = 32; off > 0; off >>= 1) s += __shfl_xor(s, off);
  if (lane == 0) {
    const float4* ps4 = (const float4*)&psum[(size_t)row * MSPLIT];
    float4 q0 = ps4[0], q1 = ps4[1];
    float tot = ((q0.x + q0.y) + (q0.z + q0.w)) + ((q1.x + q1.y) + (q1.z + q1.w));
    float term = logf(tot) - s * 0.1f;
    part[w] = fminf(term, 92.103403719761827f);   // ratio clip at 1e-40
  }
  __syncthreads();
  if (threadIdx.x == 0)
    blockpart[blockIdx.x] = part[0] + part[1] + part[2] + part[3];
}

// ---- kernel 4: final deterministic reduction ------------------------------
__global__ __launch_bounds__(256) void k_final(const float* __restrict__ blockpart,
                                               float* __restrict__ out) {
  __shared__ float red[256];
  float s = 0.0f;
  for (int i = threadIdx.x; i < (BB * NN) / 4; i += 256) s += blockpart[i];
  red[threadIdx.x] = s;
  __syncthreads();
  for (int st = 128; st > 0; st >>= 1) {
    if (threadIdx.x < st) red[threadIdx.x] += red[threadIdx.x + st];
    __syncthreads();
  }
  if (threadIdx.x == 0) out[0] = red[0] * (1.0f / (BB * NN));
}

extern "C" void kernel_launch(void* const* d_in, const int* in_sizes, int n_in,
                              void* d_out, int out_size, void* d_ws, size_t ws_size,
                              hipStream_t stream) {
  const float* fs = (const float*)d_in[0];
  const float* ft = (const float*)d_in[1];
  float* out = (float*)d_out;

  const size_t NE = (size_t)BB * NN * DD;
  unsigned short* fsb = (unsigned short*)d_ws;                    // 4MB
  unsigned short* ftb = fsb + NE;                                 // 4MB
  float*  inv_norm = (float*)(ftb + NE);                          // 64KB
  float*  psum     = inv_norm + (size_t)BB * NN;                  // B*N*8 f32
  float2* pmaxvi   = (float2*)(psum + (size_t)BB * NN * MSPLIT);  // B*N*128 f32x2
  float*  blockpart = (float*)(pmaxvi + (size_t)BB * NN * NP);    // B*N/4 f32

  k_prep<<<(2 * BB * NN) / 4, 256, 0, stream>>>(fs, ft, (unsigned*)fsb, inv_norm);
  dim3 g2(NN / 128, MSPLIT, BB);
  k_main<<<g2, 256, 0, stream>>>(fsb, ftb, inv_norm, psum, pmaxvi);
  k_post<<<(BB * NN) / 4, 256, 0, stream>>>(fs, ft, psum, pmaxvi, blockpart);
  k_final<<<1, 256, 0, stream>>>(blockpart, out);
}